// Round 11
// baseline (483.125 us; speedup 1.0000x reference)
//
#include <hip/hip_runtime.h>

#define NGn 100000
#define NDn 20000
#define EGGn 1000000
#define EGDn 500000
#define Dn 128
#define NT (NGn + NDn)
#define ET (EGGn + EGDn)
#define NBK ((NT + 255) / 256)          // 469 buckets of 256 nodes
#define P2B 512                          // histogram/scatter blocks (2*256 for sub_scan pairing)
#define CHUNK ((ET + P2B - 1) / P2B)     // 2930 edges per block

typedef unsigned short u16;
typedef unsigned int u32;
typedef __attribute__((ext_vector_type(8))) short short8;   // 8 bf16 in 4 VGPRs (verified MFMA frag type)
typedef __attribute__((ext_vector_type(4))) float f32x4;

__device__ __forceinline__ float blo(u32 u) { return __uint_as_float(u << 16); }
__device__ __forceinline__ float bhi(u32 u) { return __uint_as_float(u & 0xffff0000u); }
__device__ __forceinline__ u16 f2bf(float f) {
    u32 u = __float_as_uint(f);
    u32 r = (u + 0x7fffu + ((u >> 16) & 1u)) >> 16;
    return (u16)r;
}

// wave-local dtype probe: 64 lanes sample even u16s of x; bf16 exponents cluster in [110,135]
__device__ __forceinline__ int probe_bf16(const u16* __restrict__ x) {
    int lane = threadIdx.x & 63;
    u16 v = x[2 * lane];
    int e = (v >> 7) & 0xFF;
    unsigned long long m = __ballot(e >= 110 && e <= 135);
    return __popcll(m) >= 32;   // 1 = bf16 device buffers, 0 = f32
}

// ================= K1: [convert_x (f32 only, vectorized) | convert_w/vec | P1 bucket-count] ====
#define NBX 15000                       // (NT*Dn)/1024 exactly
#define NBW 12
__global__ __launch_bounds__(256) void prep_all(
    const void* __restrict__ xg0, const void* __restrict__ xd0,
    const void* w0, const void* w1, const void* w2, const void* w3,
    const void* a0, const void* a1, const void* a2, const void* a3,
    u16* __restrict__ og, u16* __restrict__ od,
    u16* __restrict__ wbT, u16* __restrict__ vb,
    const int* __restrict__ dst_gg, const int* __restrict__ dst_gd,
    u32* __restrict__ bucketCnt, u32* __restrict__ cntMat)
{
    __shared__ u32 hist[NBK];
    int bx = blockIdx.x;
    int t = threadIdx.x;
    if (bx < NBX) {
        int f = probe_bf16((const u16*)xg0);
        if (f) return;   // bf16 inputs are consumed in place by layer-0 GEMM; no copy needed
        int i4 = (bx * 256 + t) * 4;     // 4 floats per thread; NGn*Dn divisible by 4
        const int n1 = NGn * Dn;
        const float4* src; u16* dst; int j4;
        if (i4 < n1) { src = (const float4*)xg0; dst = og; j4 = i4; }
        else         { src = (const float4*)xd0; dst = od; j4 = i4 - n1; }
        float4 v = src[j4 >> 2];
        uint2 pack;
        pack.x = (u32)f2bf(v.x) | ((u32)f2bf(v.y) << 16);
        pack.y = (u32)f2bf(v.z) | ((u32)f2bf(v.w) << 16);
        *reinterpret_cast<uint2*>(dst + j4) = pack;
    } else if (bx < NBX + NBW) {
        int f = probe_bf16((const u16*)xg0);
        int sub = bx - NBX;
        if (sub < 8) {
            const void* srcs[4] = {w0, w1, w2, w3};
            const void* sp = srcs[sub >> 1];
            int ebase = (sub & 1) * (Dn * Dn);
            size_t mbase = (size_t)sub * (Dn * Dn);
            for (int i = t; i < Dn * Dn; i += 256) {
                u16 v = f ? ((const u16*)sp)[ebase + i] : f2bf(((const float*)sp)[ebase + i]);
                wbT[mbase + (size_t)((i & 127) << 7) + (i >> 7)] = v;
            }
        } else {
            const void* srcs[4] = {a0, a1, a2, a3};
            const void* sp = srcs[sub - 8];
            u16 v = f ? ((const u16*)sp)[t] : f2bf(((const float*)sp)[t]);
            vb[(sub - 8) * 256 + t] = v;
        }
    } else {
        // P1: LDS-privatized coarse histogram over NBK buckets; publish row + global totals
        int sub = bx - NBX - NBW;
        for (int i = t; i < NBK; i += 256) hist[i] = 0;
        __syncthreads();
        int lo = sub * CHUNK, hi = min(ET, lo + CHUNK);
        for (int i = lo + t; i < hi; i += 256) {
            int d = (i < EGGn) ? dst_gg[i] : (NGn + dst_gd[i - EGGn]);
            atomicAdd(&hist[d >> 8], 1u);
        }
        __syncthreads();
        for (int i = t; i < NBK; i += 256) {
            u32 h = hist[i];
            cntMat[(size_t)sub * NBK + i] = h;
            if (h) atomicAdd(&bucketCnt[i], h);
        }
    }
}

// ================= K2: scan bucket counts -> bucket bases =================
__global__ __launch_bounds__(256) void scan_buckets(
    const u32* __restrict__ bucketCnt, u32* __restrict__ bbase)
{
    __shared__ u32 sh[256];
    int t = threadIdx.x;
    u32 carry = 0;
    for (int base = 0; base < NBK; base += 256) {
        int i = base + t;
        u32 v = (i < NBK) ? bucketCnt[i] : 0;
        sh[t] = v;
        __syncthreads();
#pragma unroll
        for (int off = 1; off < 256; off <<= 1) {
            u32 a = (t >= off) ? sh[t - off] : 0;
            __syncthreads();
            sh[t] += a;
            __syncthreads();
        }
        if (i < NBK) bbase[i] = carry + sh[t] - v;
        u32 chunk = sh[255];
        __syncthreads();
        carry += chunk;
    }
    if (t == 0) bbase[NBK] = carry;
}

// ================= K2c: per-bucket scan over the P2B sub-blocks -> exact write bases ==========
__global__ __launch_bounds__(256) void sub_scan(
    const u32* __restrict__ cntMat, const u32* __restrict__ bbase, u32* __restrict__ baseMat)
{
    __shared__ u32 sh[256];
    int b = blockIdx.x, t = threadIdx.x;
    u32 v0 = cntMat[(size_t)(2 * t) * NBK + b];
    u32 v1 = cntMat[(size_t)(2 * t + 1) * NBK + b];
    u32 pair = v0 + v1;
    sh[t] = pair;
    __syncthreads();
#pragma unroll
    for (int off = 1; off < 256; off <<= 1) {
        u32 a = (t >= off) ? sh[t - off] : 0;
        __syncthreads();
        sh[t] += a;
        __syncthreads();
    }
    u32 excl = sh[t] - pair;
    u32 bb = bbase[b];
    baseMat[(size_t)(2 * t) * NBK + b]     = bb + excl;
    baseMat[(size_t)(2 * t + 1) * NBK + b] = bb + excl + v0;
}

// ================= MFMA GEMM body — ks-outer / nt-inner, 8 independent accumulators =========
#define GG_BLK ((NGn + 63) / 64)   // 1563
#define GD_BLK ((NDn + 63) / 64)   // 313
#define LDB(KS) do { \
    b0 = Wof[0*256 + (KS)*4]; b1 = Wof[1*256 + (KS)*4]; \
    b2 = Wof[2*256 + (KS)*4]; b3 = Wof[3*256 + (KS)*4]; \
    b4 = Wof[4*256 + (KS)*4]; b5 = Wof[5*256 + (KS)*4]; \
    b6 = Wof[6*256 + (KS)*4]; b7 = Wof[7*256 + (KS)*4]; } while (0)
#define MFMA8(A) do { \
    c0 = __builtin_amdgcn_mfma_f32_16x16x32_bf16(A, b0, c0, 0, 0, 0); \
    c1 = __builtin_amdgcn_mfma_f32_16x16x32_bf16(A, b1, c1, 0, 0, 0); \
    c2 = __builtin_amdgcn_mfma_f32_16x16x32_bf16(A, b2, c2, 0, 0, 0); \
    c3 = __builtin_amdgcn_mfma_f32_16x16x32_bf16(A, b3, c3, 0, 0, 0); \
    c4 = __builtin_amdgcn_mfma_f32_16x16x32_bf16(A, b4, c4, 0, 0, 0); \
    c5 = __builtin_amdgcn_mfma_f32_16x16x32_bf16(A, b5, c5, 0, 0, 0); \
    c6 = __builtin_amdgcn_mfma_f32_16x16x32_bf16(A, b6, c6, 0, 0, 0); \
    c7 = __builtin_amdgcn_mfma_f32_16x16x32_bf16(A, b7, c7, 0, 0, 0); } while (0)
#define STORE_NT(NT, CV) do { \
    int cidx = (NT)*16 + r; \
    int rw0 = row0 + g*4; \
    if (rw0 + 0 < M) Y[(size_t)(rw0 + 0) * Dn + cidx] = f2bf(CV[0]); \
    if (rw0 + 1 < M) Y[(size_t)(rw0 + 1) * Dn + cidx] = f2bf(CV[1]); \
    if (rw0 + 2 < M) Y[(size_t)(rw0 + 2) * Dn + cidx] = f2bf(CV[2]); \
    if (rw0 + 3 < M) Y[(size_t)(rw0 + 3) * Dn + cidx] = f2bf(CV[3]); } while (0)

__device__ __forceinline__ void gemm_body(
    int gbx,
    const u16* __restrict__ Xg, const u16* __restrict__ Xd,
    const u16* __restrict__ WTg0, const u16* __restrict__ WTg1, const u16* __restrict__ WTg2,
    const u16* __restrict__ WTd,
    u16* __restrict__ Y0, u16* __restrict__ Y1, u16* __restrict__ Y2, u16* __restrict__ Y3)
{
    int wv = threadIdx.x >> 6, lane = threadIdx.x & 63;
    int r = lane & 15, g = lane >> 4;
    bool gene = gbx < GG_BLK;
    int blk = gene ? gbx : gbx - GG_BLK;
    int M = gene ? NGn : NDn;
    const u16* X = gene ? Xg : Xd;
    int row0 = blk * 64 + wv * 16;
    if (row0 >= M) return;                     // wave-uniform
    int arow = row0 + r; if (arow >= M) arow = M - 1;
    const short8* Xa = reinterpret_cast<const short8*>(X + (size_t)arow * Dn);
    short8 a0 = Xa[g], a1 = Xa[4 + g], a2 = Xa[8 + g], a3 = Xa[12 + g];

    int no = gene ? 3 : 1;
    for (int o = 0; o < no; ++o) {
        const u16* Wt = gene ? ((o == 0) ? WTg0 : (o == 1) ? WTg1 : WTg2) : WTd;
        u16* Y = gene ? ((o == 0) ? Y0 : (o == 1) ? Y1 : Y2) : Y3;
        const short8* Wof = reinterpret_cast<const short8*>(Wt) + (size_t)r * 16 + g;
        f32x4 c0 = {0,0,0,0}, c1 = {0,0,0,0}, c2 = {0,0,0,0}, c3 = {0,0,0,0};
        f32x4 c4 = {0,0,0,0}, c5 = {0,0,0,0}, c6 = {0,0,0,0}, c7 = {0,0,0,0};
        short8 b0, b1, b2, b3, b4, b5, b6, b7;
        LDB(0); MFMA8(a0);     // 8 independent loads -> 8 independent MFMAs, no dep chain
        LDB(1); MFMA8(a1);
        LDB(2); MFMA8(a2);
        LDB(3); MFMA8(a3);
        STORE_NT(0, c0); STORE_NT(1, c1); STORE_NT(2, c2); STORE_NT(3, c3);
        STORE_NT(4, c4); STORE_NT(5, c5); STORE_NT(6, c6); STORE_NT(7, c7);
    }
}

// ================= K3: [P2 single-pass scatter (no atomics, no hist) | gemm layer 0] ==========
__global__ __launch_bounds__(256) void scatter_gemm(
    const int* __restrict__ src_gg, const int* __restrict__ dst_gg,
    const int* __restrict__ src_gd, const int* __restrict__ dst_gd,
    const u32* __restrict__ baseMat, u32* __restrict__ staging,
    const u16* __restrict__ xg0, const u16* __restrict__ xd0,   // raw inputs (maybe bf16)
    const u16* __restrict__ Xgc, const u16* __restrict__ Xdc,   // converted (f32 case)
    const u16* __restrict__ WTg0, const u16* __restrict__ WTg1, const u16* __restrict__ WTg2,
    const u16* __restrict__ WTd,
    u16* __restrict__ Y0, u16* __restrict__ Y1, u16* __restrict__ Y2, u16* __restrict__ Y3)
{
    __shared__ u32 cur[NBK];
    __shared__ u32 lbase[NBK];
    int bx = blockIdx.x;
    if (bx < P2B) {
        int t = threadIdx.x;
        for (int i = t; i < NBK; i += 256) {
            lbase[i] = baseMat[(size_t)bx * NBK + i];   // exact precomputed region base
            cur[i] = 0;
        }
        __syncthreads();
        int lo = bx * CHUNK, hi = min(ET, lo + CHUNK);
        for (int i = lo + t; i < hi; i += 256) {
            int s, d;
            if (i < EGGn) { s = src_gg[i]; d = dst_gg[i]; }
            else          { s = src_gd[i - EGGn]; d = NGn + dst_gd[i - EGGn]; }
            int bk = d >> 8;
            u32 off = atomicAdd(&cur[bk], 1u);          // LDS-only cursor
            staging[lbase[bk] + off] = ((u32)s << 8) | (u32)(d & 255);
        }
    } else {
        int f = probe_bf16(xg0);
        const u16* Xg = f ? xg0 : Xgc;
        const u16* Xd = f ? xd0 : Xdc;
        gemm_body(bx - P2B, Xg, Xd, WTg0, WTg1, WTg2, WTd, Y0, Y1, Y2, Y3);
    }
}

// ================= K4: fine CSR within each bucket =================
__global__ __launch_bounds__(256) void fine_csr(
    const u32* __restrict__ bbase, const u32* __restrict__ staging,
    u32* __restrict__ rp, u32* __restrict__ deg, int* __restrict__ col)
{
    __shared__ u32 hist[256];
    __shared__ u32 sh[256];
    __shared__ u32 ex[256];
    int b = blockIdx.x, t = threadIdx.x;
    int base = (int)bbase[b], end = (int)bbase[b + 1];
    hist[t] = 0;
    __syncthreads();
    for (int i = base + t; i < end; i += 256)
        atomicAdd(&hist[staging[i] & 255u], 1u);
    __syncthreads();
    u32 v = hist[t];
    sh[t] = v;
    __syncthreads();
#pragma unroll
    for (int off = 1; off < 256; off <<= 1) {
        u32 a = (t >= off) ? sh[t - off] : 0;
        __syncthreads();
        sh[t] += a;
        __syncthreads();
    }
    ex[t] = sh[t] - v;
    int node = b * 256 + t;
    if (node < NT) { deg[node] = v; rp[node] = base + ex[t]; }
    hist[t] = 0;   // reuse as placement cursor
    __syncthreads();
    for (int i = base + t; i < end; i += 256) {
        u32 pv = staging[i];
        u32 n = pv & 255u;
        u32 off2 = atomicAdd(&hist[n], 1u);
        col[base + ex[n] + off2] = (int)(pv >> 8);
    }
}

// ================= K6: gemm layer 1 =================
__global__ __launch_bounds__(256) void gemm_only(
    const u16* __restrict__ Xg, const u16* __restrict__ Xd,
    const u16* __restrict__ WTg0, const u16* __restrict__ WTg1, const u16* __restrict__ WTg2,
    const u16* __restrict__ WTd,
    u16* __restrict__ Y0, u16* __restrict__ Y1, u16* __restrict__ Y2, u16* __restrict__ Y3)
{
    gemm_body(blockIdx.x, Xg, Xd, WTg0, WTg1, WTg2, WTd, Y0, Y1, Y2, Y3);
}

// ================= K5/K7: fused GATv2 gather, 8 edges/iter (2 slots/lane), 16 lanes/edge ======
// blocks [0,25000): gg section; [25000,30000): gd section   (unchanged from round-10 PASS)
#define SCORE8(RV, VALID, SC) do {                                                   \
    float x0_=blo(RV.x), x1_=bhi(RV.x), x2_=blo(RV.y), x3_=bhi(RV.y);                \
    float x4_=blo(RV.z), x5_=bhi(RV.z), x6_=blo(RV.w), x7_=bhi(RV.w);                \
    float t0_ = x0_ + xr0; t0_ = fmaxf(t0_, 0.2f * t0_);                             \
    float t1_ = x1_ + xr1; t1_ = fmaxf(t1_, 0.2f * t1_);                             \
    float t2_ = x2_ + xr2; t2_ = fmaxf(t2_, 0.2f * t2_);                             \
    float t3_ = x3_ + xr3; t3_ = fmaxf(t3_, 0.2f * t3_);                             \
    float t4_ = x4_ + xr4; t4_ = fmaxf(t4_, 0.2f * t4_);                             \
    float t5_ = x5_ + xr5; t5_ = fmaxf(t5_, 0.2f * t5_);                             \
    float t6_ = x6_ + xr6; t6_ = fmaxf(t6_, 0.2f * t6_);                             \
    float t7_ = x7_ + xr7; t7_ = fmaxf(t7_, 0.2f * t7_);                             \
    float sc_ = t0_*at0 + t1_*at1 + t2_*at2 + t3_*at3                                \
              + t4_*at4 + t5_*at5 + t6_*at6 + t7_*at7;                               \
    sc_ += __shfl_xor(sc_, 4);                                                       \
    sc_ += __shfl_xor(sc_, 8);                                                       \
    sc_ += __shfl_xor(sc_, 16);                                                      \
    sc_ += __shfl_xor(sc_, 32);                                                      \
    SC = (VALID) ? sc_ : -1.0e30f;                                                   \
} while (0)

__global__ __launch_bounds__(256) void gat_gather(
    const u16* __restrict__ xl_g, const u16* __restrict__ xr_g,
    const u16* __restrict__ xl_d, const u16* __restrict__ xr_d,
    const u32* __restrict__ rp, const u32* __restrict__ deg, const int* __restrict__ col,
    const u16* __restrict__ vb, int l,
    void* __restrict__ yg, void* __restrict__ yd,
    const u16* __restrict__ xg0probe, int to_out)
{
    int wv = threadIdx.x >> 6, lane = threadIdx.x & 63;
    bool gg = blockIdx.x < 25000;
    int blk = gg ? blockIdx.x : blockIdx.x - 25000;
    int d = blk * 4 + wv;
    int N = gg ? NGn : NDn;
    if (d >= N) return;   // wave-uniform
    const u16* xl_sel = gg ? xl_g : xl_d;
    const u16* xr_sel = gg ? xr_g : xr_d;
    int nodeid = d + (gg ? 0 : NGn);
    const u16* att = vb + (gg ? 0 : 512) + l * Dn;
    const u16* bv  = vb + (gg ? 256 : 768) + l * Dn;
    void* y = gg ? yg : yd;
    size_t yoff = (gg || !to_out) ? 0 : (size_t)NGn * Dn;   // concat offset only for final output

    int h = lane & 3;        // edge slot pair: edges pb+h and pb+h+4
    int qq = lane >> 2;      // channel group: 8 ch, qq*8..qq*8+7

    uint4 rv = *reinterpret_cast<const uint4*>(xr_sel + (size_t)d * Dn + qq * 8);
    float xr0 = blo(rv.x), xr1 = bhi(rv.x), xr2 = blo(rv.y), xr3 = bhi(rv.y);
    float xr4 = blo(rv.z), xr5 = bhi(rv.z), xr6 = blo(rv.w), xr7 = bhi(rv.w);
    const float L2E = 1.44269504f;   // log2 domain -> native v_exp_f32
    uint4 av = *reinterpret_cast<const uint4*>(att + qq * 8);
    float at0 = blo(av.x) * L2E, at1 = bhi(av.x) * L2E;
    float at2 = blo(av.y) * L2E, at3 = bhi(av.y) * L2E;
    float at4 = blo(av.z) * L2E, at5 = bhi(av.z) * L2E;
    float at6 = blo(av.w) * L2E, at7 = bhi(av.w) * L2E;

    int p0 = (int)rp[nodeid], p1 = p0 + (int)deg[nodeid];
    float s = 0.f;
    float ac0 = 0.f, ac1 = 0.f, ac2 = 0.f, ac3 = 0.f;
    float ac4 = 0.f, ac5 = 0.f, ac6 = 0.f, ac7 = 0.f;

    uint4 ra = make_uint4(0,0,0,0), rb = make_uint4(0,0,0,0);
    bool va = false, vb2 = false;
    if (p0 < p1) {
        int ea = p0 + h;     va  = ea < p1;
        int eb = p0 + h + 4; vb2 = eb < p1;
        int sa = col[va  ? ea : p0];
        int sb = col[vb2 ? eb : p0];
        ra = *reinterpret_cast<const uint4*>(xl_sel + (size_t)sa * Dn + qq * 8);
        rb = *reinterpret_cast<const uint4*>(xl_sel + (size_t)sb * Dn + qq * 8);
    }
    for (int pb = p0; pb < p1; pb += 8) {
        uint4 na = make_uint4(0,0,0,0), nb = make_uint4(0,0,0,0);
        bool vna = false, vnb = false;
        if (pb + 8 < p1) {
            int ea = pb + 8 + h;     vna = ea < p1;
            int eb = pb + 8 + h + 4; vnb = eb < p1;
            int sa = col[vna ? ea : p0];
            int sb = col[vnb ? eb : p0];
            na = *reinterpret_cast<const uint4*>(xl_sel + (size_t)sa * Dn + qq * 8);
            nb = *reinterpret_cast<const uint4*>(xl_sel + (size_t)sb * Dn + qq * 8);
        }
        float sca, scb;
        SCORE8(ra, va, sca);
        SCORE8(rb, vb2, scb);
        float pea = __builtin_amdgcn_exp2f(sca);   // invalid slot -> exp2(-1e30) = 0
        float peb = __builtin_amdgcn_exp2f(scb);
        s += pea + peb;
        ac0 += pea * blo(ra.x) + peb * blo(rb.x);
        ac1 += pea * bhi(ra.x) + peb * bhi(rb.x);
        ac2 += pea * blo(ra.y) + peb * blo(rb.y);
        ac3 += pea * bhi(ra.y) + peb * bhi(rb.y);
        ac4 += pea * blo(ra.z) + peb * blo(rb.z);
        ac5 += pea * bhi(ra.z) + peb * bhi(rb.z);
        ac6 += pea * blo(ra.w) + peb * blo(rb.w);
        ac7 += pea * bhi(ra.w) + peb * bhi(rb.w);
        ra = na; rb = nb; va = vna; vb2 = vnb;
    }
    // merge the 4 slot-lanes (exact softmax: plain adds across xor 1,2)
    s   += __shfl_xor(s, 1);   s   += __shfl_xor(s, 2);
    ac0 += __shfl_xor(ac0, 1); ac0 += __shfl_xor(ac0, 2);
    ac1 += __shfl_xor(ac1, 1); ac1 += __shfl_xor(ac1, 2);
    ac2 += __shfl_xor(ac2, 1); ac2 += __shfl_xor(ac2, 2);
    ac3 += __shfl_xor(ac3, 1); ac3 += __shfl_xor(ac3, 2);
    ac4 += __shfl_xor(ac4, 1); ac4 += __shfl_xor(ac4, 2);
    ac5 += __shfl_xor(ac5, 1); ac5 += __shfl_xor(ac5, 2);
    ac6 += __shfl_xor(ac6, 1); ac6 += __shfl_xor(ac6, 2);
    ac7 += __shfl_xor(ac7, 1); ac7 += __shfl_xor(ac7, 2);
    float inv = (s > 0.f) ? __builtin_amdgcn_rcpf(s) : 0.f;
    uint4 bu = *reinterpret_cast<const uint4*>(bv + qq * 8);
    float o0 = ac0 * inv + blo(bu.x), o1 = ac1 * inv + bhi(bu.x);
    float o2 = ac2 * inv + blo(bu.y), o3 = ac3 * inv + bhi(bu.y);
    float o4 = ac4 * inv + blo(bu.z), o5 = ac5 * inv + bhi(bu.z);
    float o6 = ac6 * inv + blo(bu.w), o7 = ac7 * inv + bhi(bu.w);
    if (h != 0) return;
    int f = to_out ? probe_bf16(xg0probe) : 1;
    if (to_out && f == 0) {
        float* yf = (float*)y + yoff + (size_t)d * Dn + qq * 8;
        *reinterpret_cast<float4*>(yf)     = make_float4(o0, o1, o2, o3);
        *reinterpret_cast<float4*>(yf + 4) = make_float4(o4, o5, o6, o7);
    } else {
        uint4 pack;
        pack.x = (u32)f2bf(o0) | ((u32)f2bf(o1) << 16);
        pack.y = (u32)f2bf(o2) | ((u32)f2bf(o3) << 16);
        pack.z = (u32)f2bf(o4) | ((u32)f2bf(o5) << 16);
        pack.w = (u32)f2bf(o6) | ((u32)f2bf(o7) << 16);
        *reinterpret_cast<uint4*>((u16*)y + yoff + (size_t)d * Dn + qq * 8) = pack;
    }
}

extern "C" void kernel_launch(void* const* d_in, const int* in_sizes, int n_in,
                              void* d_out, int out_size, void* d_ws, size_t ws_size,
                              hipStream_t stream) {
    (void)in_sizes; (void)n_in; (void)out_size;
    const void* xg0     = d_in[0];
    const void* xd0     = d_in[1];
    const int* src_gg   = (const int*)d_in[2];
    const int* dst_gg   = (const int*)d_in[3];
    const int* src_gd   = (const int*)d_in[4];
    const int* dst_gd   = (const int*)d_in[5];
    const void* Wsrc_gg = d_in[6];
    const void* Wdst_gg = d_in[7];
    const void* att_gg  = d_in[8];
    const void* b_gg    = d_in[9];
    const void* Wsrc_gd = d_in[10];
    const void* Wdst_gd = d_in[11];
    const void* att_gd  = d_in[12];
    const void* b_gd    = d_in[13];

    char* base = (char*)d_ws;
    size_t off = 0;
    auto alloc = [&](size_t bytes) -> void* {
        void* r = base + off;
        off += (bytes + 255) & ~(size_t)255;
        return r;
    };
    u16*   wbT     = (u16*)  alloc((size_t)8 * Dn * Dn * 2);
    u16*   vb      = (u16*)  alloc((size_t)4 * 256 * 2);  // 0:att_gg 1:b_gg 2:att_gd 3:b_gd
    u16*   xg_bf   = (u16*)  alloc((size_t)NGn * Dn * 2);
    u16*   xd_bf   = (u16*)  alloc((size_t)NDn * Dn * 2);
    u16*   xl_gg   = (u16*)  alloc((size_t)NGn * Dn * 2);
    u16*   xr_gg   = (u16*)  alloc((size_t)NGn * Dn * 2);
    u16*   xl_gd   = (u16*)  alloc((size_t)NGn * Dn * 2);
    u16*   xr_gd   = (u16*)  alloc((size_t)NDn * Dn * 2);
    u32*   bucketCnt = (u32*)alloc((size_t)NBK * 4);
    u32*   bbase   = (u32*)  alloc((size_t)(NBK + 1) * 4);
    u32*   cntMat  = (u32*)  alloc((size_t)P2B * NBK * 4);
    u32*   baseMat = (u32*)  alloc((size_t)P2B * NBK * 4);
    u32*   staging = (u32*)  alloc((size_t)ET * 4);
    u32*   rp      = (u32*)  alloc((size_t)NT * 4);
    u32*   deg     = (u32*)  alloc((size_t)NT * 4);
    int*   col     = (int*)  alloc((size_t)ET * 4);
    if (off > ws_size) return;

    hipMemsetAsync(bucketCnt, 0, (size_t)NBK * 4, stream);
    prep_all<<<NBX + NBW + P2B, 256, 0, stream>>>(
        xg0, xd0, Wsrc_gg, Wdst_gg, Wsrc_gd, Wdst_gd,
        att_gg, b_gg, att_gd, b_gd,
        xg_bf, xd_bf, wbT, vb, dst_gg, dst_gd, bucketCnt, cntMat);
    scan_buckets<<<1, 256, 0, stream>>>(bucketCnt, bbase);
    sub_scan<<<NBK, 256, 0, stream>>>(cntMat, bbase, baseMat);

    const u16* wT = wbT;   // [mat][layer] order: 0=Wsrc_gg 1=Wdst_gg 2=Wsrc_gd 3=Wdst_gd
    scatter_gemm<<<P2B + GG_BLK + GD_BLK, 256, 0, stream>>>(
        src_gg, dst_gg, src_gd, dst_gd, baseMat, staging,
        (const u16*)xg0, (const u16*)xd0, xg_bf, xd_bf,
        wT + (size_t)(0 * 2 + 0) * Dn * Dn, wT + (size_t)(1 * 2 + 0) * Dn * Dn,
        wT + (size_t)(2 * 2 + 0) * Dn * Dn, wT + (size_t)(3 * 2 + 0) * Dn * Dn,
        xl_gg, xr_gg, xl_gd, xr_gd);
    fine_csr<<<NBK, 256, 0, stream>>>(bbase, staging, rp, deg, col);

    gat_gather<<<30000, 256, 0, stream>>>(
        xl_gg, xr_gg, xl_gd, xr_gd, rp, deg, col, vb, 0,
        xg_bf, xd_bf, (const u16*)xg0, 0);

    gemm_only<<<GG_BLK + GD_BLK, 256, 0, stream>>>(
        xg_bf, xd_bf,
        wT + (size_t)(0 * 2 + 1) * Dn * Dn, wT + (size_t)(1 * 2 + 1) * Dn * Dn,
        wT + (size_t)(2 * 2 + 1) * Dn * Dn, wT + (size_t)(3 * 2 + 1) * Dn * Dn,
        xl_gg, xr_gg, xl_gd, xr_gd);
    gat_gather<<<30000, 256, 0, stream>>>(
        xl_gg, xr_gg, xl_gd, xr_gd, rp, deg, col, vb, 1,
        d_out, d_out, (const u16*)xg0, 1);
}

// Round 12
// 450.717 us; speedup vs baseline: 1.0719x; 1.0719x over previous
//
#include <hip/hip_runtime.h>

#define NGn 100000
#define NDn 20000
#define EGGn 1000000
#define EGDn 500000
#define Dn 128
#define NT (NGn + NDn)
#define ET (EGGn + EGDn)
#define NBK ((NT + 255) / 256)          // 469 buckets of 256 nodes
#define P2B 128                          // histogram/scatter blocks (round-10 known-good)
#define CHUNK ((ET + P2B - 1) / P2B)     // 11719 edges per block

typedef unsigned short u16;
typedef unsigned int u32;
typedef __attribute__((ext_vector_type(8))) short short8;   // 8 bf16 in 4 VGPRs (verified MFMA frag type)
typedef __attribute__((ext_vector_type(4))) float f32x4;

__device__ __forceinline__ float blo(u32 u) { return __uint_as_float(u << 16); }
__device__ __forceinline__ float bhi(u32 u) { return __uint_as_float(u & 0xffff0000u); }
__device__ __forceinline__ u16 f2bf(float f) {
    u32 u = __float_as_uint(f);
    u32 r = (u + 0x7fffu + ((u >> 16) & 1u)) >> 16;
    return (u16)r;
}

// wave-local dtype probe: 64 lanes sample even u16s of x; bf16 exponents cluster in [110,135]
__device__ __forceinline__ int probe_bf16(const u16* __restrict__ x) {
    int lane = threadIdx.x & 63;
    u16 v = x[2 * lane];
    int e = (v >> 7) & 0xFF;
    unsigned long long m = __ballot(e >= 110 && e <= 135);
    return __popcll(m) >= 32;   // 1 = bf16 device buffers, 0 = f32
}

// ================= K1: [convert_x (f32 only, vectorized) | convert_w/vec | P1 bucket-count] ====
#define NBX 15000                       // (NT*Dn)/1024 exactly
#define NBW 12
__global__ __launch_bounds__(256) void prep_all(
    const void* __restrict__ xg0, const void* __restrict__ xd0,
    const void* w0, const void* w1, const void* w2, const void* w3,
    const void* a0, const void* a1, const void* a2, const void* a3,
    u16* __restrict__ og, u16* __restrict__ od,
    u16* __restrict__ wbT, u16* __restrict__ vb,
    const int* __restrict__ dst_gg, const int* __restrict__ dst_gd,
    u32* __restrict__ bucketCnt)
{
    __shared__ u32 hist[NBK];
    int bx = blockIdx.x;
    int t = threadIdx.x;
    if (bx < NBX) {
        int f = probe_bf16((const u16*)xg0);
        if (f) return;   // bf16 inputs are consumed in place by layer-0 GEMM; no copy needed
        int i4 = (bx * 256 + t) * 4;     // 4 floats per thread; NGn*Dn divisible by 4
        const int n1 = NGn * Dn;
        const float4* src; u16* dst; int j4;
        if (i4 < n1) { src = (const float4*)xg0; dst = og; j4 = i4; }
        else         { src = (const float4*)xd0; dst = od; j4 = i4 - n1; }
        float4 v = src[j4 >> 2];
        uint2 pack;
        pack.x = (u32)f2bf(v.x) | ((u32)f2bf(v.y) << 16);
        pack.y = (u32)f2bf(v.z) | ((u32)f2bf(v.w) << 16);
        *reinterpret_cast<uint2*>(dst + j4) = pack;
    } else if (bx < NBX + NBW) {
        int f = probe_bf16((const u16*)xg0);
        int sub = bx - NBX;
        if (sub < 8) {
            const void* srcs[4] = {w0, w1, w2, w3};
            const void* sp = srcs[sub >> 1];
            int ebase = (sub & 1) * (Dn * Dn);
            size_t mbase = (size_t)sub * (Dn * Dn);
            for (int i = t; i < Dn * Dn; i += 256) {
                u16 v = f ? ((const u16*)sp)[ebase + i] : f2bf(((const float*)sp)[ebase + i]);
                wbT[mbase + (size_t)((i & 127) << 7) + (i >> 7)] = v;
            }
        } else {
            const void* srcs[4] = {a0, a1, a2, a3};
            const void* sp = srcs[sub - 8];
            u16 v = f ? ((const u16*)sp)[t] : f2bf(((const float*)sp)[t]);
            vb[(sub - 8) * 256 + t] = v;
        }
    } else {
        // P1: LDS-privatized coarse histogram over NBK buckets
        int sub = bx - NBX - NBW;
        for (int i = t; i < NBK; i += 256) hist[i] = 0;
        __syncthreads();
        int lo = sub * CHUNK, hi = min(ET, lo + CHUNK);
        for (int i = lo + t; i < hi; i += 256) {
            int d = (i < EGGn) ? dst_gg[i] : (NGn + dst_gd[i - EGGn]);
            atomicAdd(&hist[d >> 8], 1u);
        }
        __syncthreads();
        for (int i = t; i < NBK; i += 256)
            if (hist[i]) atomicAdd(&bucketCnt[i], hist[i]);
    }
}

// ================= K2: scan bucket counts -> bases + cursors =================
__global__ __launch_bounds__(256) void scan_buckets(
    const u32* __restrict__ bucketCnt, u32* __restrict__ bbase, u32* __restrict__ bcur)
{
    __shared__ u32 sh[256];
    int t = threadIdx.x;
    u32 carry = 0;
    for (int base = 0; base < NBK; base += 256) {
        int i = base + t;
        u32 v = (i < NBK) ? bucketCnt[i] : 0;
        sh[t] = v;
        __syncthreads();
#pragma unroll
        for (int off = 1; off < 256; off <<= 1) {
            u32 a = (t >= off) ? sh[t - off] : 0;
            __syncthreads();
            sh[t] += a;
            __syncthreads();
        }
        if (i < NBK) { u32 e = carry + sh[t] - v; bbase[i] = e; bcur[i] = e; }
        u32 chunk = sh[255];
        __syncthreads();
        carry += chunk;
    }
    if (t == 0) bbase[NBK] = carry;
}

// ================= MFMA GEMM body — ks-outer / nt-inner, 8 independent accumulators =========
#define GG_BLK ((NGn + 63) / 64)   // 1563
#define GD_BLK ((NDn + 63) / 64)   // 313
#define LDB(KS) do { \
    b0 = Wof[0*256 + (KS)*4]; b1 = Wof[1*256 + (KS)*4]; \
    b2 = Wof[2*256 + (KS)*4]; b3 = Wof[3*256 + (KS)*4]; \
    b4 = Wof[4*256 + (KS)*4]; b5 = Wof[5*256 + (KS)*4]; \
    b6 = Wof[6*256 + (KS)*4]; b7 = Wof[7*256 + (KS)*4]; } while (0)
#define MFMA8(A) do { \
    c0 = __builtin_amdgcn_mfma_f32_16x16x32_bf16(A, b0, c0, 0, 0, 0); \
    c1 = __builtin_amdgcn_mfma_f32_16x16x32_bf16(A, b1, c1, 0, 0, 0); \
    c2 = __builtin_amdgcn_mfma_f32_16x16x32_bf16(A, b2, c2, 0, 0, 0); \
    c3 = __builtin_amdgcn_mfma_f32_16x16x32_bf16(A, b3, c3, 0, 0, 0); \
    c4 = __builtin_amdgcn_mfma_f32_16x16x32_bf16(A, b4, c4, 0, 0, 0); \
    c5 = __builtin_amdgcn_mfma_f32_16x16x32_bf16(A, b5, c5, 0, 0, 0); \
    c6 = __builtin_amdgcn_mfma_f32_16x16x32_bf16(A, b6, c6, 0, 0, 0); \
    c7 = __builtin_amdgcn_mfma_f32_16x16x32_bf16(A, b7, c7, 0, 0, 0); } while (0)
#define STORE_NT(NT, CV) do { \
    int cidx = (NT)*16 + r; \
    int rw0 = row0 + g*4; \
    if (rw0 + 0 < M) Y[(size_t)(rw0 + 0) * Dn + cidx] = f2bf(CV[0]); \
    if (rw0 + 1 < M) Y[(size_t)(rw0 + 1) * Dn + cidx] = f2bf(CV[1]); \
    if (rw0 + 2 < M) Y[(size_t)(rw0 + 2) * Dn + cidx] = f2bf(CV[2]); \
    if (rw0 + 3 < M) Y[(size_t)(rw0 + 3) * Dn + cidx] = f2bf(CV[3]); } while (0)

__device__ __forceinline__ void gemm_body(
    int gbx,
    const u16* __restrict__ Xg, const u16* __restrict__ Xd,
    const u16* __restrict__ WTg0, const u16* __restrict__ WTg1, const u16* __restrict__ WTg2,
    const u16* __restrict__ WTd,
    u16* __restrict__ Y0, u16* __restrict__ Y1, u16* __restrict__ Y2, u16* __restrict__ Y3)
{
    int wv = threadIdx.x >> 6, lane = threadIdx.x & 63;
    int r = lane & 15, g = lane >> 4;
    bool gene = gbx < GG_BLK;
    int blk = gene ? gbx : gbx - GG_BLK;
    int M = gene ? NGn : NDn;
    const u16* X = gene ? Xg : Xd;
    int row0 = blk * 64 + wv * 16;
    if (row0 >= M) return;                     // wave-uniform
    int arow = row0 + r; if (arow >= M) arow = M - 1;
    const short8* Xa = reinterpret_cast<const short8*>(X + (size_t)arow * Dn);
    short8 a0 = Xa[g], a1 = Xa[4 + g], a2 = Xa[8 + g], a3 = Xa[12 + g];

    int no = gene ? 3 : 1;
    for (int o = 0; o < no; ++o) {
        const u16* Wt = gene ? ((o == 0) ? WTg0 : (o == 1) ? WTg1 : WTg2) : WTd;
        u16* Y = gene ? ((o == 0) ? Y0 : (o == 1) ? Y1 : Y2) : Y3;
        const short8* Wof = reinterpret_cast<const short8*>(Wt) + (size_t)r * 16 + g;
        f32x4 c0 = {0,0,0,0}, c1 = {0,0,0,0}, c2 = {0,0,0,0}, c3 = {0,0,0,0};
        f32x4 c4 = {0,0,0,0}, c5 = {0,0,0,0}, c6 = {0,0,0,0}, c7 = {0,0,0,0};
        short8 b0, b1, b2, b3, b4, b5, b6, b7;
        LDB(0); MFMA8(a0);     // 8 independent loads -> 8 independent MFMAs, no dep chain
        LDB(1); MFMA8(a1);
        LDB(2); MFMA8(a2);
        LDB(3); MFMA8(a3);
        STORE_NT(0, c0); STORE_NT(1, c1); STORE_NT(2, c2); STORE_NT(3, c3);
        STORE_NT(4, c4); STORE_NT(5, c5); STORE_NT(6, c6); STORE_NT(7, c7);
    }
}

// ================= K3: [P2 bucket-scatter (round-10 bulk-reserve) | gemm layer 0] =============
__global__ __launch_bounds__(256) void scatter_gemm(
    const int* __restrict__ src_gg, const int* __restrict__ dst_gg,
    const int* __restrict__ src_gd, const int* __restrict__ dst_gd,
    u32* __restrict__ bcur, u32* __restrict__ staging,
    const u16* __restrict__ xg0, const u16* __restrict__ xd0,   // raw inputs (maybe bf16)
    const u16* __restrict__ Xgc, const u16* __restrict__ Xdc,   // converted (f32 case)
    const u16* __restrict__ WTg0, const u16* __restrict__ WTg1, const u16* __restrict__ WTg2,
    const u16* __restrict__ WTd,
    u16* __restrict__ Y0, u16* __restrict__ Y1, u16* __restrict__ Y2, u16* __restrict__ Y3)
{
    __shared__ u32 hist[NBK];
    __shared__ u32 lbase[NBK];
    int bx = blockIdx.x;
    if (bx < P2B) {
        int t = threadIdx.x;
        for (int i = t; i < NBK; i += 256) hist[i] = 0;
        __syncthreads();
        int lo = bx * CHUNK, hi = min(ET, lo + CHUNK);
        for (int i = lo + t; i < hi; i += 256) {
            int d = (i < EGGn) ? dst_gg[i] : (NGn + dst_gd[i - EGGn]);
            atomicAdd(&hist[d >> 8], 1u);
        }
        __syncthreads();
        for (int i = t; i < NBK; i += 256)
            lbase[i] = hist[i] ? atomicAdd(&bcur[i], hist[i]) : 0;
        __syncthreads();
        for (int i = t; i < NBK; i += 256) hist[i] = 0;   // reuse as local cursor
        __syncthreads();
        for (int i = lo + t; i < hi; i += 256) {
            int s, d;
            if (i < EGGn) { s = src_gg[i]; d = dst_gg[i]; }
            else          { s = src_gd[i - EGGn]; d = NGn + dst_gd[i - EGGn]; }
            int bk = d >> 8;
            u32 off = atomicAdd(&hist[bk], 1u);
            staging[lbase[bk] + off] = ((u32)s << 8) | (u32)(d & 255);
        }
    } else {
        int f = probe_bf16(xg0);
        const u16* Xg = f ? xg0 : Xgc;
        const u16* Xd = f ? xd0 : Xdc;
        gemm_body(bx - P2B, Xg, Xd, WTg0, WTg1, WTg2, WTd, Y0, Y1, Y2, Y3);
    }
}

// ================= K4: fine CSR within each bucket =================
__global__ __launch_bounds__(256) void fine_csr(
    const u32* __restrict__ bbase, const u32* __restrict__ staging,
    u32* __restrict__ rp, u32* __restrict__ deg, int* __restrict__ col)
{
    __shared__ u32 hist[256];
    __shared__ u32 sh[256];
    __shared__ u32 ex[256];
    int b = blockIdx.x, t = threadIdx.x;
    int base = (int)bbase[b], end = (int)bbase[b + 1];
    hist[t] = 0;
    __syncthreads();
    for (int i = base + t; i < end; i += 256)
        atomicAdd(&hist[staging[i] & 255u], 1u);
    __syncthreads();
    u32 v = hist[t];
    sh[t] = v;
    __syncthreads();
#pragma unroll
    for (int off = 1; off < 256; off <<= 1) {
        u32 a = (t >= off) ? sh[t - off] : 0;
        __syncthreads();
        sh[t] += a;
        __syncthreads();
    }
    ex[t] = sh[t] - v;
    int node = b * 256 + t;
    if (node < NT) { deg[node] = v; rp[node] = base + ex[t]; }
    hist[t] = 0;   // reuse as placement cursor
    __syncthreads();
    for (int i = base + t; i < end; i += 256) {
        u32 pv = staging[i];
        u32 n = pv & 255u;
        u32 off2 = atomicAdd(&hist[n], 1u);
        col[base + ex[n] + off2] = (int)(pv >> 8);
    }
}

// ================= K6: gemm layer 1 =================
__global__ __launch_bounds__(256) void gemm_only(
    const u16* __restrict__ Xg, const u16* __restrict__ Xd,
    const u16* __restrict__ WTg0, const u16* __restrict__ WTg1, const u16* __restrict__ WTg2,
    const u16* __restrict__ WTd,
    u16* __restrict__ Y0, u16* __restrict__ Y1, u16* __restrict__ Y2, u16* __restrict__ Y3)
{
    gemm_body(blockIdx.x, Xg, Xd, WTg0, WTg1, WTg2, WTd, Y0, Y1, Y2, Y3);
}

// ================= K5/K7: fused GATv2 gather — 2 nodes/wave, 4-edge granularity ==============
// blocks [0,12500): gg (8 nodes/block); [12500,15000): gd.  Per 32-lane half: one node,
// h=lane&1 edge parity, qq=(lane>>1)&15 channel group (8 ch), 2-deep ILP (slots pb+h, pb+2+h).
#define GGB (NGn / 8)   // 12500
#define GDB (NDn / 8)   // 2500
#define SCORE8(RV, VALID, SC) do {                                                   \
    float x0_=blo(RV.x), x1_=bhi(RV.x), x2_=blo(RV.y), x3_=bhi(RV.y);                \
    float x4_=blo(RV.z), x5_=bhi(RV.z), x6_=blo(RV.w), x7_=bhi(RV.w);                \
    float t0_ = x0_ + xr0; t0_ = fmaxf(t0_, 0.2f * t0_);                             \
    float t1_ = x1_ + xr1; t1_ = fmaxf(t1_, 0.2f * t1_);                             \
    float t2_ = x2_ + xr2; t2_ = fmaxf(t2_, 0.2f * t2_);                             \
    float t3_ = x3_ + xr3; t3_ = fmaxf(t3_, 0.2f * t3_);                             \
    float t4_ = x4_ + xr4; t4_ = fmaxf(t4_, 0.2f * t4_);                             \
    float t5_ = x5_ + xr5; t5_ = fmaxf(t5_, 0.2f * t5_);                             \
    float t6_ = x6_ + xr6; t6_ = fmaxf(t6_, 0.2f * t6_);                             \
    float t7_ = x7_ + xr7; t7_ = fmaxf(t7_, 0.2f * t7_);                             \
    float sc_ = t0_*at0 + t1_*at1 + t2_*at2 + t3_*at3                                \
              + t4_*at4 + t5_*at5 + t6_*at6 + t7_*at7;                               \
    sc_ += __shfl_xor(sc_, 2);                                                       \
    sc_ += __shfl_xor(sc_, 4);                                                       \
    sc_ += __shfl_xor(sc_, 8);                                                       \
    sc_ += __shfl_xor(sc_, 16);                                                      \
    SC = (VALID) ? sc_ : -1.0e30f;                                                   \
} while (0)

__global__ __launch_bounds__(256) void gat_gather(
    const u16* __restrict__ xl_g, const u16* __restrict__ xr_g,
    const u16* __restrict__ xl_d, const u16* __restrict__ xr_d,
    const u32* __restrict__ rp, const u32* __restrict__ deg, const int* __restrict__ col,
    const u16* __restrict__ vb, int l,
    void* __restrict__ yg, void* __restrict__ yd,
    const u16* __restrict__ xg0probe, int to_out)
{
    int wv = threadIdx.x >> 6, lane = threadIdx.x & 63;
    bool gg = blockIdx.x < GGB;
    int blk = gg ? blockIdx.x : blockIdx.x - GGB;
    int sub = lane >> 5;                        // sub-node within wave
    int d = blk * 8 + wv * 2 + sub;             // exact division: no tail checks needed
    const u16* xl_sel = gg ? xl_g : xl_d;
    const u16* xr_sel = gg ? xr_g : xr_d;
    int nodeid = d + (gg ? 0 : NGn);
    const u16* att = vb + (gg ? 0 : 512) + l * Dn;
    const u16* bv  = vb + (gg ? 256 : 768) + l * Dn;
    void* y = gg ? yg : yd;
    size_t yoff = (gg || !to_out) ? 0 : (size_t)NGn * Dn;   // concat offset only for final output

    int h = lane & 1;          // edge slot parity
    int qq = (lane >> 1) & 15; // channel group: 8 ch, qq*8..qq*8+7

    uint4 rv = *reinterpret_cast<const uint4*>(xr_sel + (size_t)d * Dn + qq * 8);
    float xr0 = blo(rv.x), xr1 = bhi(rv.x), xr2 = blo(rv.y), xr3 = bhi(rv.y);
    float xr4 = blo(rv.z), xr5 = bhi(rv.z), xr6 = blo(rv.w), xr7 = bhi(rv.w);
    const float L2E = 1.44269504f;   // log2 domain -> native v_exp_f32
    uint4 av = *reinterpret_cast<const uint4*>(att + qq * 8);
    float at0 = blo(av.x) * L2E, at1 = bhi(av.x) * L2E;
    float at2 = blo(av.y) * L2E, at3 = bhi(av.y) * L2E;
    float at4 = blo(av.z) * L2E, at5 = bhi(av.z) * L2E;
    float at6 = blo(av.w) * L2E, at7 = bhi(av.w) * L2E;

    int p0 = (int)rp[nodeid], p1 = p0 + (int)deg[nodeid];
    float s = 0.f;
    float ac0 = 0.f, ac1 = 0.f, ac2 = 0.f, ac3 = 0.f;
    float ac4 = 0.f, ac5 = 0.f, ac6 = 0.f, ac7 = 0.f;

    uint4 ra = make_uint4(0,0,0,0), rb = make_uint4(0,0,0,0);
    bool va = false, vb2 = false;
    if (p0 < p1) {
        int ea = p0 + h;     va  = ea < p1;
        int eb = p0 + 2 + h; vb2 = eb < p1;
        int sa = col[va  ? ea : p0];
        int sb = col[vb2 ? eb : p0];
        ra = *reinterpret_cast<const uint4*>(xl_sel + (size_t)sa * Dn + qq * 8);
        rb = *reinterpret_cast<const uint4*>(xl_sel + (size_t)sb * Dn + qq * 8);
    }
    for (int pb = p0; pb < p1; pb += 4) {
        uint4 na = make_uint4(0,0,0,0), nb = make_uint4(0,0,0,0);
        bool vna = false, vnb = false;
        if (pb + 4 < p1) {
            int ea = pb + 4 + h;     vna = ea < p1;
            int eb = pb + 6 + h;     vnb = eb < p1;
            int sa = col[vna ? ea : p0];
            int sb = col[vnb ? eb : p0];
            na = *reinterpret_cast<const uint4*>(xl_sel + (size_t)sa * Dn + qq * 8);
            nb = *reinterpret_cast<const uint4*>(xl_sel + (size_t)sb * Dn + qq * 8);
        }
        float sca, scb;
        SCORE8(ra, va, sca);
        SCORE8(rb, vb2, scb);
        float pea = __builtin_amdgcn_exp2f(sca);   // invalid slot -> exp2(-1e30) = 0
        float peb = __builtin_amdgcn_exp2f(scb);
        s += pea + peb;
        ac0 += pea * blo(ra.x) + peb * blo(rb.x);
        ac1 += pea * bhi(ra.x) + peb * bhi(rb.x);
        ac2 += pea * blo(ra.y) + peb * blo(rb.y);
        ac3 += pea * bhi(ra.y) + peb * bhi(rb.y);
        ac4 += pea * blo(ra.z) + peb * blo(rb.z);
        ac5 += pea * bhi(ra.z) + peb * bhi(rb.z);
        ac6 += pea * blo(ra.w) + peb * blo(rb.w);
        ac7 += pea * bhi(ra.w) + peb * bhi(rb.w);
        ra = na; rb = nb; va = vna; vb2 = vnb;
    }
    // merge the 2 slot parities (exact softmax: plain adds across xor 1)
    s   += __shfl_xor(s, 1);
    ac0 += __shfl_xor(ac0, 1);
    ac1 += __shfl_xor(ac1, 1);
    ac2 += __shfl_xor(ac2, 1);
    ac3 += __shfl_xor(ac3, 1);
    ac4 += __shfl_xor(ac4, 1);
    ac5 += __shfl_xor(ac5, 1);
    ac6 += __shfl_xor(ac6, 1);
    ac7 += __shfl_xor(ac7, 1);
    float inv = (s > 0.f) ? __builtin_amdgcn_rcpf(s) : 0.f;
    uint4 bu = *reinterpret_cast<const uint4*>(bv + qq * 8);
    float o0 = ac0 * inv + blo(bu.x), o1 = ac1 * inv + bhi(bu.x);
    float o2 = ac2 * inv + blo(bu.y), o3 = ac3 * inv + bhi(bu.y);
    float o4 = ac4 * inv + blo(bu.z), o5 = ac5 * inv + bhi(bu.z);
    float o6 = ac6 * inv + blo(bu.w), o7 = ac7 * inv + bhi(bu.w);
    if (h != 0) return;
    int f = to_out ? probe_bf16(xg0probe) : 1;
    if (to_out && f == 0) {
        float* yf = (float*)y + yoff + (size_t)d * Dn + qq * 8;
        *reinterpret_cast<float4*>(yf)     = make_float4(o0, o1, o2, o3);
        *reinterpret_cast<float4*>(yf + 4) = make_float4(o4, o5, o6, o7);
    } else {
        uint4 pack;
        pack.x = (u32)f2bf(o0) | ((u32)f2bf(o1) << 16);
        pack.y = (u32)f2bf(o2) | ((u32)f2bf(o3) << 16);
        pack.z = (u32)f2bf(o4) | ((u32)f2bf(o5) << 16);
        pack.w = (u32)f2bf(o6) | ((u32)f2bf(o7) << 16);
        *reinterpret_cast<uint4*>((u16*)y + yoff + (size_t)d * Dn + qq * 8) = pack;
    }
}

extern "C" void kernel_launch(void* const* d_in, const int* in_sizes, int n_in,
                              void* d_out, int out_size, void* d_ws, size_t ws_size,
                              hipStream_t stream) {
    (void)in_sizes; (void)n_in; (void)out_size;
    const void* xg0     = d_in[0];
    const void* xd0     = d_in[1];
    const int* src_gg   = (const int*)d_in[2];
    const int* dst_gg   = (const int*)d_in[3];
    const int* src_gd   = (const int*)d_in[4];
    const int* dst_gd   = (const int*)d_in[5];
    const void* Wsrc_gg = d_in[6];
    const void* Wdst_gg = d_in[7];
    const void* att_gg  = d_in[8];
    const void* b_gg    = d_in[9];
    const void* Wsrc_gd = d_in[10];
    const void* Wdst_gd = d_in[11];
    const void* att_gd  = d_in[12];
    const void* b_gd    = d_in[13];

    char* base = (char*)d_ws;
    size_t off = 0;
    auto alloc = [&](size_t bytes) -> void* {
        void* r = base + off;
        off += (bytes + 255) & ~(size_t)255;
        return r;
    };
    u16*   wbT     = (u16*)  alloc((size_t)8 * Dn * Dn * 2);
    u16*   vb      = (u16*)  alloc((size_t)4 * 256 * 2);  // 0:att_gg 1:b_gg 2:att_gd 3:b_gd
    u16*   xg_bf   = (u16*)  alloc((size_t)NGn * Dn * 2);
    u16*   xd_bf   = (u16*)  alloc((size_t)NDn * Dn * 2);
    u16*   xl_gg   = (u16*)  alloc((size_t)NGn * Dn * 2);
    u16*   xr_gg   = (u16*)  alloc((size_t)NGn * Dn * 2);
    u16*   xl_gd   = (u16*)  alloc((size_t)NGn * Dn * 2);
    u16*   xr_gd   = (u16*)  alloc((size_t)NDn * Dn * 2);
    u32*   bucketCnt = (u32*)alloc((size_t)NBK * 4);
    u32*   bbase   = (u32*)  alloc((size_t)(NBK + 1) * 4);
    u32*   bcur    = (u32*)  alloc((size_t)NBK * 4);
    u32*   staging = (u32*)  alloc((size_t)ET * 4);
    u32*   rp      = (u32*)  alloc((size_t)NT * 4);
    u32*   deg     = (u32*)  alloc((size_t)NT * 4);
    int*   col     = (int*)  alloc((size_t)ET * 4);
    if (off > ws_size) return;

    hipMemsetAsync(bucketCnt, 0, (size_t)NBK * 4, stream);
    prep_all<<<NBX + NBW + P2B, 256, 0, stream>>>(
        xg0, xd0, Wsrc_gg, Wdst_gg, Wsrc_gd, Wdst_gd,
        att_gg, b_gg, att_gd, b_gd,
        xg_bf, xd_bf, wbT, vb, dst_gg, dst_gd, bucketCnt);
    scan_buckets<<<1, 256, 0, stream>>>(bucketCnt, bbase, bcur);

    const u16* wT = wbT;   // [mat][layer] order: 0=Wsrc_gg 1=Wdst_gg 2=Wsrc_gd 3=Wdst_gd
    scatter_gemm<<<P2B + GG_BLK + GD_BLK, 256, 0, stream>>>(
        src_gg, dst_gg, src_gd, dst_gd, bcur, staging,
        (const u16*)xg0, (const u16*)xd0, xg_bf, xd_bf,
        wT + (size_t)(0 * 2 + 0) * Dn * Dn, wT + (size_t)(1 * 2 + 0) * Dn * Dn,
        wT + (size_t)(2 * 2 + 0) * Dn * Dn, wT + (size_t)(3 * 2 + 0) * Dn * Dn,
        xl_gg, xr_gg, xl_gd, xr_gd);
    fine_csr<<<NBK, 256, 0, stream>>>(bbase, staging, rp, deg, col);

    gat_gather<<<GGB + GDB, 256, 0, stream>>>(
        xl_gg, xr_gg, xl_gd, xr_gd, rp, deg, col, vb, 0,
        xg_bf, xd_bf, (const u16*)xg0, 0);

    gemm_only<<<GG_BLK + GD_BLK, 256, 0, stream>>>(
        xg_bf, xd_bf,
        wT + (size_t)(0 * 2 + 1) * Dn * Dn, wT + (size_t)(1 * 2 + 1) * Dn * Dn,
        wT + (size_t)(2 * 2 + 1) * Dn * Dn, wT + (size_t)(3 * 2 + 1) * Dn * Dn,
        xl_gg, xr_gg, xl_gd, xr_gd);
    gat_gather<<<GGB + GDB, 256, 0, stream>>>(
        xl_gg, xr_gg, xl_gd, xr_gd, rp, deg, col, vb, 1,
        d_out, d_out, (const u16*)xg0, 1);
}

// Round 13
// 428.395 us; speedup vs baseline: 1.1278x; 1.0521x over previous
//
#include <hip/hip_runtime.h>

#define NGn 100000
#define NDn 20000
#define EGGn 1000000
#define EGDn 500000
#define Dn 128
#define NT (NGn + NDn)
#define ET (EGGn + EGDn)
#define NBK ((NT + 255) / 256)          // 469 buckets of 256 nodes
#define P2B 128                          // histogram/scatter blocks (round-10 known-good)
#define CHUNK ((ET + P2B - 1) / P2B)     // 11719 edges per block

typedef unsigned short u16;
typedef unsigned int u32;
typedef __attribute__((ext_vector_type(8))) short short8;   // 8 bf16 in 4 VGPRs (verified MFMA frag type)
typedef __attribute__((ext_vector_type(4))) float f32x4;

__device__ __forceinline__ float blo(u32 u) { return __uint_as_float(u << 16); }
__device__ __forceinline__ float bhi(u32 u) { return __uint_as_float(u & 0xffff0000u); }
__device__ __forceinline__ u16 f2bf(float f) {
    u32 u = __float_as_uint(f);
    u32 r = (u + 0x7fffu + ((u >> 16) & 1u)) >> 16;
    return (u16)r;
}

// wave-local dtype probe: 64 lanes sample even u16s of x; bf16 exponents cluster in [110,135]
__device__ __forceinline__ int probe_bf16(const u16* __restrict__ x) {
    int lane = threadIdx.x & 63;
    u16 v = x[2 * lane];
    int e = (v >> 7) & 0xFF;
    unsigned long long m = __ballot(e >= 110 && e <= 135);
    return __popcll(m) >= 32;   // 1 = bf16 device buffers, 0 = f32
}

// ================= K1: [convert_x (f32 only, vectorized) | convert_w/vec | P1 bucket-count] ====
#define NBX 15000                       // (NT*Dn)/1024 exactly
#define NBW 12
__global__ __launch_bounds__(256) void prep_all(
    const void* __restrict__ xg0, const void* __restrict__ xd0,
    const void* w0, const void* w1, const void* w2, const void* w3,
    const void* a0, const void* a1, const void* a2, const void* a3,
    u16* __restrict__ og, u16* __restrict__ od,
    u16* __restrict__ wbT, u16* __restrict__ vb,
    const int* __restrict__ dst_gg, const int* __restrict__ dst_gd,
    u32* __restrict__ bucketCnt, u32* __restrict__ cntMat)
{
    __shared__ u32 hist[NBK];
    int bx = blockIdx.x;
    int t = threadIdx.x;
    if (bx < NBX) {
        int f = probe_bf16((const u16*)xg0);
        if (f) return;   // bf16 inputs are consumed in place by layer-0 GEMM; no copy needed
        int i4 = (bx * 256 + t) * 4;     // 4 floats per thread; NGn*Dn divisible by 4
        const int n1 = NGn * Dn;
        const float4* src; u16* dst; int j4;
        if (i4 < n1) { src = (const float4*)xg0; dst = og; j4 = i4; }
        else         { src = (const float4*)xd0; dst = od; j4 = i4 - n1; }
        float4 v = src[j4 >> 2];
        uint2 pack;
        pack.x = (u32)f2bf(v.x) | ((u32)f2bf(v.y) << 16);
        pack.y = (u32)f2bf(v.z) | ((u32)f2bf(v.w) << 16);
        *reinterpret_cast<uint2*>(dst + j4) = pack;
    } else if (bx < NBX + NBW) {
        int f = probe_bf16((const u16*)xg0);
        int sub = bx - NBX;
        if (sub < 8) {
            const void* srcs[4] = {w0, w1, w2, w3};
            const void* sp = srcs[sub >> 1];
            int ebase = (sub & 1) * (Dn * Dn);
            size_t mbase = (size_t)sub * (Dn * Dn);
            for (int i = t; i < Dn * Dn; i += 256) {
                u16 v = f ? ((const u16*)sp)[ebase + i] : f2bf(((const float*)sp)[ebase + i]);
                wbT[mbase + (size_t)((i & 127) << 7) + (i >> 7)] = v;
            }
        } else {
            const void* srcs[4] = {a0, a1, a2, a3};
            const void* sp = srcs[sub - 8];
            u16 v = f ? ((const u16*)sp)[t] : f2bf(((const float*)sp)[t]);
            vb[(sub - 8) * 256 + t] = v;
        }
    } else {
        // P1: LDS-privatized coarse histogram over NBK buckets; persist row for P2 reuse
        int sub = bx - NBX - NBW;
        for (int i = t; i < NBK; i += 256) hist[i] = 0;
        __syncthreads();
        int lo = sub * CHUNK, hi = min(ET, lo + CHUNK);
        for (int i = lo + t; i < hi; i += 256) {
            int d = (i < EGGn) ? dst_gg[i] : (NGn + dst_gd[i - EGGn]);
            atomicAdd(&hist[d >> 8], 1u);
        }
        __syncthreads();
        for (int i = t; i < NBK; i += 256) {
            u32 h = hist[i];
            cntMat[(size_t)sub * NBK + i] = h;      // P2 reads this instead of re-counting
            if (h) atomicAdd(&bucketCnt[i], h);
        }
    }
}

// ================= K2: scan bucket counts -> bases + cursors =================
__global__ __launch_bounds__(256) void scan_buckets(
    const u32* __restrict__ bucketCnt, u32* __restrict__ bbase, u32* __restrict__ bcur)
{
    __shared__ u32 sh[256];
    int t = threadIdx.x;
    u32 carry = 0;
    for (int base = 0; base < NBK; base += 256) {
        int i = base + t;
        u32 v = (i < NBK) ? bucketCnt[i] : 0;
        sh[t] = v;
        __syncthreads();
#pragma unroll
        for (int off = 1; off < 256; off <<= 1) {
            u32 a = (t >= off) ? sh[t - off] : 0;
            __syncthreads();
            sh[t] += a;
            __syncthreads();
        }
        if (i < NBK) { u32 e = carry + sh[t] - v; bbase[i] = e; bcur[i] = e; }
        u32 chunk = sh[255];
        __syncthreads();
        carry += chunk;
    }
    if (t == 0) bbase[NBK] = carry;
}

// ================= MFMA GEMM body — ks-outer / nt-inner, 8 independent accumulators =========
#define GG_BLK ((NGn + 63) / 64)   // 1563
#define GD_BLK ((NDn + 63) / 64)   // 313
#define LDB(KS) do { \
    b0 = Wof[0*256 + (KS)*4]; b1 = Wof[1*256 + (KS)*4]; \
    b2 = Wof[2*256 + (KS)*4]; b3 = Wof[3*256 + (KS)*4]; \
    b4 = Wof[4*256 + (KS)*4]; b5 = Wof[5*256 + (KS)*4]; \
    b6 = Wof[6*256 + (KS)*4]; b7 = Wof[7*256 + (KS)*4]; } while (0)
#define MFMA8(A) do { \
    c0 = __builtin_amdgcn_mfma_f32_16x16x32_bf16(A, b0, c0, 0, 0, 0); \
    c1 = __builtin_amdgcn_mfma_f32_16x16x32_bf16(A, b1, c1, 0, 0, 0); \
    c2 = __builtin_amdgcn_mfma_f32_16x16x32_bf16(A, b2, c2, 0, 0, 0); \
    c3 = __builtin_amdgcn_mfma_f32_16x16x32_bf16(A, b3, c3, 0, 0, 0); \
    c4 = __builtin_amdgcn_mfma_f32_16x16x32_bf16(A, b4, c4, 0, 0, 0); \
    c5 = __builtin_amdgcn_mfma_f32_16x16x32_bf16(A, b5, c5, 0, 0, 0); \
    c6 = __builtin_amdgcn_mfma_f32_16x16x32_bf16(A, b6, c6, 0, 0, 0); \
    c7 = __builtin_amdgcn_mfma_f32_16x16x32_bf16(A, b7, c7, 0, 0, 0); } while (0)
#define STORE_NT(NT, CV) do { \
    int cidx = (NT)*16 + r; \
    int rw0 = row0 + g*4; \
    if (rw0 + 0 < M) Y[(size_t)(rw0 + 0) * Dn + cidx] = f2bf(CV[0]); \
    if (rw0 + 1 < M) Y[(size_t)(rw0 + 1) * Dn + cidx] = f2bf(CV[1]); \
    if (rw0 + 2 < M) Y[(size_t)(rw0 + 2) * Dn + cidx] = f2bf(CV[2]); \
    if (rw0 + 3 < M) Y[(size_t)(rw0 + 3) * Dn + cidx] = f2bf(CV[3]); } while (0)

__device__ __forceinline__ void gemm_body(
    int gbx,
    const u16* __restrict__ Xg, const u16* __restrict__ Xd,
    const u16* __restrict__ WTg0, const u16* __restrict__ WTg1, const u16* __restrict__ WTg2,
    const u16* __restrict__ WTd,
    u16* __restrict__ Y0, u16* __restrict__ Y1, u16* __restrict__ Y2, u16* __restrict__ Y3)
{
    int wv = threadIdx.x >> 6, lane = threadIdx.x & 63;
    int r = lane & 15, g = lane >> 4;
    bool gene = gbx < GG_BLK;
    int blk = gene ? gbx : gbx - GG_BLK;
    int M = gene ? NGn : NDn;
    const u16* X = gene ? Xg : Xd;
    int row0 = blk * 64 + wv * 16;
    if (row0 >= M) return;                     // wave-uniform
    int arow = row0 + r; if (arow >= M) arow = M - 1;
    const short8* Xa = reinterpret_cast<const short8*>(X + (size_t)arow * Dn);
    short8 a0 = Xa[g], a1 = Xa[4 + g], a2 = Xa[8 + g], a3 = Xa[12 + g];

    int no = gene ? 3 : 1;
    for (int o = 0; o < no; ++o) {
        const u16* Wt = gene ? ((o == 0) ? WTg0 : (o == 1) ? WTg1 : WTg2) : WTd;
        u16* Y = gene ? ((o == 0) ? Y0 : (o == 1) ? Y1 : Y2) : Y3;
        const short8* Wof = reinterpret_cast<const short8*>(Wt) + (size_t)r * 16 + g;
        f32x4 c0 = {0,0,0,0}, c1 = {0,0,0,0}, c2 = {0,0,0,0}, c3 = {0,0,0,0};
        f32x4 c4 = {0,0,0,0}, c5 = {0,0,0,0}, c6 = {0,0,0,0}, c7 = {0,0,0,0};
        short8 b0, b1, b2, b3, b4, b5, b6, b7;
        LDB(0); MFMA8(a0);     // 8 independent loads -> 8 independent MFMAs, no dep chain
        LDB(1); MFMA8(a1);
        LDB(2); MFMA8(a2);
        LDB(3); MFMA8(a3);
        STORE_NT(0, c0); STORE_NT(1, c1); STORE_NT(2, c2); STORE_NT(3, c3);
        STORE_NT(4, c4); STORE_NT(5, c5); STORE_NT(6, c6); STORE_NT(7, c7);
    }
}

// ================= K3: [P2 placement-only scatter (hist from P1) | gemm layer 0] ==============
__global__ __launch_bounds__(256) void scatter_gemm(
    const int* __restrict__ src_gg, const int* __restrict__ dst_gg,
    const int* __restrict__ src_gd, const int* __restrict__ dst_gd,
    u32* __restrict__ bcur, const u32* __restrict__ cntMat, u32* __restrict__ staging,
    const u16* __restrict__ xg0, const u16* __restrict__ xd0,   // raw inputs (maybe bf16)
    const u16* __restrict__ Xgc, const u16* __restrict__ Xdc,   // converted (f32 case)
    const u16* __restrict__ WTg0, const u16* __restrict__ WTg1, const u16* __restrict__ WTg2,
    const u16* __restrict__ WTd,
    u16* __restrict__ Y0, u16* __restrict__ Y1, u16* __restrict__ Y2, u16* __restrict__ Y3)
{
    __shared__ u32 hist[NBK];    // placement cursor
    __shared__ u32 lbase[NBK];
    int bx = blockIdx.x;
    if (bx < P2B) {
        int t = threadIdx.x;
        // bulk-reserve directly from P1's persisted counts; skip the re-count pass entirely
        for (int i = t; i < NBK; i += 256) {
            u32 c = cntMat[(size_t)bx * NBK + i];
            lbase[i] = c ? atomicAdd(&bcur[i], c) : 0;
            hist[i] = 0;
        }
        __syncthreads();
        int lo = bx * CHUNK, hi = min(ET, lo + CHUNK);
        for (int i = lo + t; i < hi; i += 256) {
            int s, d;
            if (i < EGGn) { s = src_gg[i]; d = dst_gg[i]; }
            else          { s = src_gd[i - EGGn]; d = NGn + dst_gd[i - EGGn]; }
            int bk = d >> 8;
            u32 off = atomicAdd(&hist[bk], 1u);
            staging[lbase[bk] + off] = ((u32)s << 8) | (u32)(d & 255);
        }
    } else {
        int f = probe_bf16(xg0);
        const u16* Xg = f ? xg0 : Xgc;
        const u16* Xd = f ? xd0 : Xdc;
        gemm_body(bx - P2B, Xg, Xd, WTg0, WTg1, WTg2, WTd, Y0, Y1, Y2, Y3);
    }
}

// ================= K4: fine CSR within each bucket =================
__global__ __launch_bounds__(256) void fine_csr(
    const u32* __restrict__ bbase, const u32* __restrict__ staging,
    u32* __restrict__ rp, u32* __restrict__ deg, int* __restrict__ col)
{
    __shared__ u32 hist[256];
    __shared__ u32 sh[256];
    __shared__ u32 ex[256];
    int b = blockIdx.x, t = threadIdx.x;
    int base = (int)bbase[b], end = (int)bbase[b + 1];
    hist[t] = 0;
    __syncthreads();
    for (int i = base + t; i < end; i += 256)
        atomicAdd(&hist[staging[i] & 255u], 1u);
    __syncthreads();
    u32 v = hist[t];
    sh[t] = v;
    __syncthreads();
#pragma unroll
    for (int off = 1; off < 256; off <<= 1) {
        u32 a = (t >= off) ? sh[t - off] : 0;
        __syncthreads();
        sh[t] += a;
        __syncthreads();
    }
    ex[t] = sh[t] - v;
    int node = b * 256 + t;
    if (node < NT) { deg[node] = v; rp[node] = base + ex[t]; }
    hist[t] = 0;   // reuse as placement cursor
    __syncthreads();
    for (int i = base + t; i < end; i += 256) {
        u32 pv = staging[i];
        u32 n = pv & 255u;
        u32 off2 = atomicAdd(&hist[n], 1u);
        col[base + ex[n] + off2] = (int)(pv >> 8);
    }
}

// ================= K6: gemm layer 1 =================
__global__ __launch_bounds__(256) void gemm_only(
    const u16* __restrict__ Xg, const u16* __restrict__ Xd,
    const u16* __restrict__ WTg0, const u16* __restrict__ WTg1, const u16* __restrict__ WTg2,
    const u16* __restrict__ WTd,
    u16* __restrict__ Y0, u16* __restrict__ Y1, u16* __restrict__ Y2, u16* __restrict__ Y3)
{
    gemm_body(blockIdx.x, Xg, Xd, WTg0, WTg1, WTg2, WTd, Y0, Y1, Y2, Y3);
}

// ================= K5/K7: fused GATv2 gather — 2 nodes/wave, 4-edge granularity ==============
// blocks [0,12500): gg (8 nodes/block); [12500,15000): gd.  Per 32-lane half: one node,
// h=lane&1 edge parity, qq=(lane>>1)&15 channel group (8 ch), 2-deep ILP (slots pb+h, pb+2+h).
#define GGB (NGn / 8)   // 12500
#define GDB (NDn / 8)   // 2500
#define SCORE8(RV, VALID, SC) do {                                                   \
    float x0_=blo(RV.x), x1_=bhi(RV.x), x2_=blo(RV.y), x3_=bhi(RV.y);                \
    float x4_=blo(RV.z), x5_=bhi(RV.z), x6_=blo(RV.w), x7_=bhi(RV.w);                \
    float t0_ = x0_ + xr0; t0_ = fmaxf(t0_, 0.2f * t0_);                             \
    float t1_ = x1_ + xr1; t1_ = fmaxf(t1_, 0.2f * t1_);                             \
    float t2_ = x2_ + xr2; t2_ = fmaxf(t2_, 0.2f * t2_);                             \
    float t3_ = x3_ + xr3; t3_ = fmaxf(t3_, 0.2f * t3_);                             \
    float t4_ = x4_ + xr4; t4_ = fmaxf(t4_, 0.2f * t4_);                             \
    float t5_ = x5_ + xr5; t5_ = fmaxf(t5_, 0.2f * t5_);                             \
    float t6_ = x6_ + xr6; t6_ = fmaxf(t6_, 0.2f * t6_);                             \
    float t7_ = x7_ + xr7; t7_ = fmaxf(t7_, 0.2f * t7_);                             \
    float sc_ = t0_*at0 + t1_*at1 + t2_*at2 + t3_*at3                                \
              + t4_*at4 + t5_*at5 + t6_*at6 + t7_*at7;                               \
    sc_ += __shfl_xor(sc_, 2);                                                       \
    sc_ += __shfl_xor(sc_, 4);                                                       \
    sc_ += __shfl_xor(sc_, 8);                                                       \
    sc_ += __shfl_xor(sc_, 16);                                                      \
    SC = (VALID) ? sc_ : -1.0e30f;                                                   \
} while (0)

__global__ __launch_bounds__(256) void gat_gather(
    const u16* __restrict__ xl_g, const u16* __restrict__ xr_g,
    const u16* __restrict__ xl_d, const u16* __restrict__ xr_d,
    const u32* __restrict__ rp, const u32* __restrict__ deg, const int* __restrict__ col,
    const u16* __restrict__ vb, int l,
    void* __restrict__ yg, void* __restrict__ yd,
    const u16* __restrict__ xg0probe, int to_out)
{
    int wv = threadIdx.x >> 6, lane = threadIdx.x & 63;
    bool gg = blockIdx.x < GGB;
    int blk = gg ? blockIdx.x : blockIdx.x - GGB;
    int sub = lane >> 5;                        // sub-node within wave
    int d = blk * 8 + wv * 2 + sub;             // exact division: no tail checks needed
    const u16* xl_sel = gg ? xl_g : xl_d;
    const u16* xr_sel = gg ? xr_g : xr_d;
    int nodeid = d + (gg ? 0 : NGn);
    const u16* att = vb + (gg ? 0 : 512) + l * Dn;
    const u16* bv  = vb + (gg ? 256 : 768) + l * Dn;
    void* y = gg ? yg : yd;
    size_t yoff = (gg || !to_out) ? 0 : (size_t)NGn * Dn;   // concat offset only for final output

    int h = lane & 1;          // edge slot parity
    int qq = (lane >> 1) & 15; // channel group: 8 ch, qq*8..qq*8+7

    uint4 rv = *reinterpret_cast<const uint4*>(xr_sel + (size_t)d * Dn + qq * 8);
    float xr0 = blo(rv.x), xr1 = bhi(rv.x), xr2 = blo(rv.y), xr3 = bhi(rv.y);
    float xr4 = blo(rv.z), xr5 = bhi(rv.z), xr6 = blo(rv.w), xr7 = bhi(rv.w);
    const float L2E = 1.44269504f;   // log2 domain -> native v_exp_f32
    uint4 av = *reinterpret_cast<const uint4*>(att + qq * 8);
    float at0 = blo(av.x) * L2E, at1 = bhi(av.x) * L2E;
    float at2 = blo(av.y) * L2E, at3 = bhi(av.y) * L2E;
    float at4 = blo(av.z) * L2E, at5 = bhi(av.z) * L2E;
    float at6 = blo(av.w) * L2E, at7 = bhi(av.w) * L2E;

    int p0 = (int)rp[nodeid], p1 = p0 + (int)deg[nodeid];
    float s = 0.f;
    float ac0 = 0.f, ac1 = 0.f, ac2 = 0.f, ac3 = 0.f;
    float ac4 = 0.f, ac5 = 0.f, ac6 = 0.f, ac7 = 0.f;

    uint4 ra = make_uint4(0,0,0,0), rb = make_uint4(0,0,0,0);
    bool va = false, vb2 = false;
    if (p0 < p1) {
        int ea = p0 + h;     va  = ea < p1;
        int eb = p0 + 2 + h; vb2 = eb < p1;
        int sa = col[va  ? ea : p0];
        int sb = col[vb2 ? eb : p0];
        ra = *reinterpret_cast<const uint4*>(xl_sel + (size_t)sa * Dn + qq * 8);
        rb = *reinterpret_cast<const uint4*>(xl_sel + (size_t)sb * Dn + qq * 8);
    }
    for (int pb = p0; pb < p1; pb += 4) {
        uint4 na = make_uint4(0,0,0,0), nb = make_uint4(0,0,0,0);
        bool vna = false, vnb = false;
        if (pb + 4 < p1) {
            int ea = pb + 4 + h;     vna = ea < p1;
            int eb = pb + 6 + h;     vnb = eb < p1;
            int sa = col[vna ? ea : p0];
            int sb = col[vnb ? eb : p0];
            na = *reinterpret_cast<const uint4*>(xl_sel + (size_t)sa * Dn + qq * 8);
            nb = *reinterpret_cast<const uint4*>(xl_sel + (size_t)sb * Dn + qq * 8);
        }
        float sca, scb;
        SCORE8(ra, va, sca);
        SCORE8(rb, vb2, scb);
        float pea = __builtin_amdgcn_exp2f(sca);   // invalid slot -> exp2(-1e30) = 0
        float peb = __builtin_amdgcn_exp2f(scb);
        s += pea + peb;
        ac0 += pea * blo(ra.x) + peb * blo(rb.x);
        ac1 += pea * bhi(ra.x) + peb * bhi(rb.x);
        ac2 += pea * blo(ra.y) + peb * blo(rb.y);
        ac3 += pea * bhi(ra.y) + peb * bhi(rb.y);
        ac4 += pea * blo(ra.z) + peb * blo(rb.z);
        ac5 += pea * bhi(ra.z) + peb * bhi(rb.z);
        ac6 += pea * blo(ra.w) + peb * blo(rb.w);
        ac7 += pea * bhi(ra.w) + peb * bhi(rb.w);
        ra = na; rb = nb; va = vna; vb2 = vnb;
    }
    // merge the 2 slot parities (exact softmax: plain adds across xor 1)
    s   += __shfl_xor(s, 1);
    ac0 += __shfl_xor(ac0, 1);
    ac1 += __shfl_xor(ac1, 1);
    ac2 += __shfl_xor(ac2, 1);
    ac3 += __shfl_xor(ac3, 1);
    ac4 += __shfl_xor(ac4, 1);
    ac5 += __shfl_xor(ac5, 1);
    ac6 += __shfl_xor(ac6, 1);
    ac7 += __shfl_xor(ac7, 1);
    float inv = (s > 0.f) ? __builtin_amdgcn_rcpf(s) : 0.f;
    uint4 bu = *reinterpret_cast<const uint4*>(bv + qq * 8);
    float o0 = ac0 * inv + blo(bu.x), o1 = ac1 * inv + bhi(bu.x);
    float o2 = ac2 * inv + blo(bu.y), o3 = ac3 * inv + bhi(bu.y);
    float o4 = ac4 * inv + blo(bu.z), o5 = ac5 * inv + bhi(bu.z);
    float o6 = ac6 * inv + blo(bu.w), o7 = ac7 * inv + bhi(bu.w);
    if (h != 0) return;
    int f = to_out ? probe_bf16(xg0probe) : 1;
    if (to_out && f == 0) {
        float* yf = (float*)y + yoff + (size_t)d * Dn + qq * 8;
        *reinterpret_cast<float4*>(yf)     = make_float4(o0, o1, o2, o3);
        *reinterpret_cast<float4*>(yf + 4) = make_float4(o4, o5, o6, o7);
    } else {
        uint4 pack;
        pack.x = (u32)f2bf(o0) | ((u32)f2bf(o1) << 16);
        pack.y = (u32)f2bf(o2) | ((u32)f2bf(o3) << 16);
        pack.z = (u32)f2bf(o4) | ((u32)f2bf(o5) << 16);
        pack.w = (u32)f2bf(o6) | ((u32)f2bf(o7) << 16);
        *reinterpret_cast<uint4*>((u16*)y + yoff + (size_t)d * Dn + qq * 8) = pack;
    }
}

extern "C" void kernel_launch(void* const* d_in, const int* in_sizes, int n_in,
                              void* d_out, int out_size, void* d_ws, size_t ws_size,
                              hipStream_t stream) {
    (void)in_sizes; (void)n_in; (void)out_size;
    const void* xg0     = d_in[0];
    const void* xd0     = d_in[1];
    const int* src_gg   = (const int*)d_in[2];
    const int* dst_gg   = (const int*)d_in[3];
    const int* src_gd   = (const int*)d_in[4];
    const int* dst_gd   = (const int*)d_in[5];
    const void* Wsrc_gg = d_in[6];
    const void* Wdst_gg = d_in[7];
    const void* att_gg  = d_in[8];
    const void* b_gg    = d_in[9];
    const void* Wsrc_gd = d_in[10];
    const void* Wdst_gd = d_in[11];
    const void* att_gd  = d_in[12];
    const void* b_gd    = d_in[13];

    char* base = (char*)d_ws;
    size_t off = 0;
    auto alloc = [&](size_t bytes) -> void* {
        void* r = base + off;
        off += (bytes + 255) & ~(size_t)255;
        return r;
    };
    u16*   wbT     = (u16*)  alloc((size_t)8 * Dn * Dn * 2);
    u16*   vb      = (u16*)  alloc((size_t)4 * 256 * 2);  // 0:att_gg 1:b_gg 2:att_gd 3:b_gd
    u16*   xg_bf   = (u16*)  alloc((size_t)NGn * Dn * 2);
    u16*   xd_bf   = (u16*)  alloc((size_t)NDn * Dn * 2);
    u16*   xl_gg   = (u16*)  alloc((size_t)NGn * Dn * 2);
    u16*   xr_gg   = (u16*)  alloc((size_t)NGn * Dn * 2);
    u16*   xl_gd   = (u16*)  alloc((size_t)NGn * Dn * 2);
    u16*   xr_gd   = (u16*)  alloc((size_t)NDn * Dn * 2);
    u32*   bucketCnt = (u32*)alloc((size_t)NBK * 4);
    u32*   bbase   = (u32*)  alloc((size_t)(NBK + 1) * 4);
    u32*   bcur    = (u32*)  alloc((size_t)NBK * 4);
    u32*   cntMat  = (u32*)  alloc((size_t)P2B * NBK * 4);
    u32*   staging = (u32*)  alloc((size_t)ET * 4);
    u32*   rp      = (u32*)  alloc((size_t)NT * 4);
    u32*   deg     = (u32*)  alloc((size_t)NT * 4);
    int*   col     = (int*)  alloc((size_t)ET * 4);
    if (off > ws_size) return;

    hipMemsetAsync(bucketCnt, 0, (size_t)NBK * 4, stream);
    prep_all<<<NBX + NBW + P2B, 256, 0, stream>>>(
        xg0, xd0, Wsrc_gg, Wdst_gg, Wsrc_gd, Wdst_gd,
        att_gg, b_gg, att_gd, b_gd,
        xg_bf, xd_bf, wbT, vb, dst_gg, dst_gd, bucketCnt, cntMat);
    scan_buckets<<<1, 256, 0, stream>>>(bucketCnt, bbase, bcur);

    const u16* wT = wbT;   // [mat][layer] order: 0=Wsrc_gg 1=Wdst_gg 2=Wsrc_gd 3=Wdst_gd
    scatter_gemm<<<P2B + GG_BLK + GD_BLK, 256, 0, stream>>>(
        src_gg, dst_gg, src_gd, dst_gd, bcur, cntMat, staging,
        (const u16*)xg0, (const u16*)xd0, xg_bf, xd_bf,
        wT + (size_t)(0 * 2 + 0) * Dn * Dn, wT + (size_t)(1 * 2 + 0) * Dn * Dn,
        wT + (size_t)(2 * 2 + 0) * Dn * Dn, wT + (size_t)(3 * 2 + 0) * Dn * Dn,
        xl_gg, xr_gg, xl_gd, xr_gd);
    fine_csr<<<NBK, 256, 0, stream>>>(bbase, staging, rp, deg, col);

    gat_gather<<<GGB + GDB, 256, 0, stream>>>(
        xl_gg, xr_gg, xl_gd, xr_gd, rp, deg, col, vb, 0,
        xg_bf, xd_bf, (const u16*)xg0, 0);

    gemm_only<<<GG_BLK + GD_BLK, 256, 0, stream>>>(
        xg_bf, xd_bf,
        wT + (size_t)(0 * 2 + 1) * Dn * Dn, wT + (size_t)(1 * 2 + 1) * Dn * Dn,
        wT + (size_t)(2 * 2 + 1) * Dn * Dn, wT + (size_t)(3 * 2 + 1) * Dn * Dn,
        xl_gg, xr_gg, xl_gd, xr_gd);
    gat_gather<<<GGB + GDB, 256, 0, stream>>>(
        xl_gg, xr_gg, xl_gd, xr_gd, rp, deg, col, vb, 1,
        d_out, d_out, (const u16*)xg0, 1);
}